// Round 2
// baseline (1267.809 us; speedup 1.0000x reference)
//
#include <hip/hip_runtime.h>

typedef _Float16 f16;
typedef _Float16 f16x8 __attribute__((ext_vector_type(8)));
typedef float f32x4 __attribute__((ext_vector_type(4)));

#define DEVI static __device__ __forceinline__

// async global->LDS 16B: lane i lands at (wave-uniform lds base) + i*16
DEVI void async_ld16(const void* g, void* l) {
  __builtin_amdgcn_global_load_lds(
      (const __attribute__((address_space(1))) unsigned int*)g,
      (__attribute__((address_space(3))) unsigned int*)l, 16, 0, 0);
}

// Byte offset of (row, logical k-quad) in a 128x32-f16 tile (64 B rows),
// XOR-swizzled so 16-lane frag reads are only 2-way bank aliased (free).
DEVI int sw_off(int row, int q) {
  return row * 64 + ((q ^ ((row >> 1) & 3)) << 4);
}

// Stage one 128x32 fp32 source tile -> fp16 LDS tile (swizzled), 256 threads.
// Each thread: row=tid>>1, 16 floats at (tid&1)*16; done in 2 chunks of 8 to
// cap live VGPRs (~8 floats) under the __launch_bounds__(256,4) 128-reg cap.
DEVI void stage_f32_tile(const float* __restrict__ src_row, f16* lds, int tid) {
  int r = tid >> 1, half = tid & 1;
#pragma unroll
  for (int u2 = 0; u2 < 2; ++u2) {
    f32x4 a = *(const f32x4*)(src_row + half * 16 + u2 * 8);
    f32x4 b = *(const f32x4*)(src_row + half * 16 + u2 * 8 + 4);
    f16x8 h;
    h[0] = (f16)a[0]; h[1] = (f16)a[1]; h[2] = (f16)a[2]; h[3] = (f16)a[3];
    h[4] = (f16)b[0]; h[5] = (f16)b[1]; h[6] = (f16)b[2]; h[7] = (f16)b[3];
    *(f16x8*)((char*)lds + sw_off(r, half * 2 + u2)) = h;
  }
}

// C[M,N] (fp32 split-K partials) = A[M,K] * B[N,K]^T.
// A fp16 (async) or fp32 (in-kernel cvt); B likewise.
// 128x128 block tile, 4 waves of 64x64, 16x16x32 f16 MFMA, BK=32.
template<bool A_F32, bool B_F32>
__global__ __launch_bounds__(256, 4)
void gemm_bt(const void* __restrict__ Aptr, const void* __restrict__ Bptr,
             float* __restrict__ Cpart, int ldK, int Nvalid,
             int mTiles, int nTiles, int kPerSplit, int Mtot) {
  __shared__ __align__(16) f16 As[128 * 32];
  __shared__ __align__(16) f16 Bs[128 * 32];

  // XCD swizzle: co-locate same-(ns,ks) M-tile groups on one XCD (grid % 8 == 0)
  int nb = gridDim.x;
  int bid = (blockIdx.x & 7) * (nb >> 3) + (blockIdx.x >> 3);
  int ms = bid % mTiles; bid /= mTiles;
  int ns = bid % nTiles; bid /= nTiles;
  int ks = bid;
  int m0 = ms * 128, n0 = ns * 128;
  int k0 = ks * kPerSplit;

  int tid = threadIdx.x;
  int w = tid >> 6, lane = tid & 63;
  int wrow = (w >> 1) * 64, wcol = (w & 1) * 64;
  int lrow = lane & 15, lquad = lane >> 4;

  f32x4 acc[4][4];
#pragma unroll
  for (int i = 0; i < 4; ++i)
#pragma unroll
    for (int j = 0; j < 4; ++j) acc[i][j] = (f32x4){0.f, 0.f, 0.f, 0.f};

  for (int kk = k0; kk < k0 + kPerSplit; kk += 32) {
    __syncthreads();  // previous iter's LDS reads done
    // ---- stage A tile ----
    if (!A_F32) {
      const f16* Ah = (const f16*)Aptr;
#pragma unroll
      for (int s = 0; s < 2; ++s) {
        int rl = w * 32 + s * 16 + (lane >> 2);
        int qp = lane & 3;
        int q = qp ^ ((rl >> 1) & 3);
        async_ld16(Ah + (size_t)(m0 + rl) * ldK + kk + q * 8, &As[(w * 32 + s * 16) * 32]);
      }
    }
    // ---- stage B tile ----
    if (!B_F32) {
      const f16* Bh = (const f16*)Bptr;
#pragma unroll
      for (int s = 0; s < 2; ++s) {
        int rl = w * 32 + s * 16 + (lane >> 2);
        int qp = lane & 3;
        int q = qp ^ ((rl >> 1) & 3);
        int rb = n0 + rl; if (rb > Nvalid - 1) rb = Nvalid - 1;  // clamp (garbage cols unstored)
        async_ld16(Bh + (size_t)rb * ldK + kk + q * 8, &Bs[(w * 32 + s * 16) * 32]);
      }
    }
    if (A_F32) {
      const float* Af = (const float*)Aptr;
      stage_f32_tile(Af + (size_t)(m0 + (tid >> 1)) * ldK + kk, As, tid);
    }
    if (B_F32) {
      const float* Bf = (const float*)Bptr;
      int rb = n0 + (tid >> 1); if (rb > Nvalid - 1) rb = Nvalid - 1;
      stage_f32_tile(Bf + (size_t)rb * ldK + kk, Bs, tid);
    }
    __syncthreads();  // drains vmcnt (async LDS) + lgkmcnt (ds_write)

    f16x8 af[4], bf[4];
#pragma unroll
    for (int i = 0; i < 4; ++i)
      af[i] = *(const f16x8*)((const char*)As + sw_off(wrow + i * 16 + lrow, lquad));
#pragma unroll
    for (int j = 0; j < 4; ++j)
      bf[j] = *(const f16x8*)((const char*)Bs + sw_off(wcol + j * 16 + lrow, lquad));
#pragma unroll
    for (int i = 0; i < 4; ++i)
#pragma unroll
      for (int j = 0; j < 4; ++j)
        acc[i][j] = __builtin_amdgcn_mfma_f32_16x16x32_f16(af[i], bf[j], acc[i][j], 0, 0, 0);
  }

  // C/D layout: col = lane&15, row = (lane>>4)*4 + reg  (m89/m91-verified)
  size_t base = (size_t)ks * Mtot * Nvalid;
#pragma unroll
  for (int i = 0; i < 4; ++i) {
    int row = m0 + wrow + i * 16 + lquad * 4;
#pragma unroll
    for (int j = 0; j < 4; ++j) {
      int col = n0 + wcol + j * 16 + lrow;
      if (col < Nvalid) {
#pragma unroll
        for (int r = 0; r < 4; ++r)
          Cpart[base + (size_t)(row + r) * Nvalid + col] = acc[i][j][r];
      }
    }
  }
}

__global__ void cvt_f32_to_f16(const float* __restrict__ in, f16* __restrict__ out, long n) {
  long idx = ((long)blockIdx.x * blockDim.x + threadIdx.x) * 8;
  if (idx + 8 <= n) {
    f32x4 a = *(const f32x4*)(in + idx);
    f32x4 b = *(const f32x4*)(in + idx + 4);
    f16x8 o;
    o[0] = (f16)a[0]; o[1] = (f16)a[1]; o[2] = (f16)a[2]; o[3] = (f16)a[3];
    o[4] = (f16)b[0]; o[5] = (f16)b[1]; o[6] = (f16)b[2]; o[7] = (f16)b[3];
    *(f16x8*)(out + idx) = o;
  }
}

// Build deform-conv columns: cols[b][c*49+p] = bilinear(x[b,c], p_tap + offset), fp16
__global__ __launch_bounds__(256)
void build_cols(const float* __restrict__ x, const float* __restrict__ offs,
                f16* __restrict__ cols) {
  int b = blockIdx.x;
  __shared__ int s_idx[49][4];
  __shared__ float s_w[49][4];
  int t = threadIdx.x;
  if (t < 49) {
    float dy = offs[b * 98 + 2 * t];
    float dx = offs[b * 98 + 2 * t + 1];
    float py = dy + (float)(t / 7);   // ky = p/7, base_y = 0
    float px = dx + (float)(t % 7);   // kx = p%7
    float fy0 = floorf(py), fx0 = floorf(px);
    int y0 = (int)fy0, x0 = (int)fx0;
    float fy = py - fy0, fx = px - fx0;
#pragma unroll
    for (int di = 0; di < 2; ++di)
#pragma unroll
      for (int dj = 0; dj < 2; ++dj) {
        int yi = y0 + di, xi = x0 + dj;
        bool valid = (yi >= 0) && (yi < 7) && (xi >= 0) && (xi < 7);
        int yc = yi < 0 ? 0 : (yi > 6 ? 6 : yi);
        int xc = xi < 0 ? 0 : (xi > 6 ? 6 : xi);
        float wy = di ? fy : 1.f - fy;
        float wx = dj ? fx : 1.f - fx;
        s_idx[t][di * 2 + dj] = yc * 7 + xc;
        s_w[t][di * 2 + dj] = valid ? wy * wx : 0.f;
      }
  }
  __syncthreads();
  const float* xb = x + (size_t)b * 50176;
  f16* cb = cols + (size_t)b * 50176;
  for (int k0 = t * 8; k0 < 50176; k0 += 256 * 8) {
    f16x8 h;
#pragma unroll
    for (int u = 0; u < 8; ++u) {
      int k = k0 + u;
      int c = k / 49;
      int p = k - c * 49;
      const float* xc = xb + c * 49;
      float v = s_w[p][0] * xc[s_idx[p][0]] + s_w[p][1] * xc[s_idx[p][1]]
              + s_w[p][2] * xc[s_idx[p][2]] + s_w[p][3] * xc[s_idx[p][3]];
      h[u] = (f16)v;
    }
    *(f16x8*)(cb + k0) = h;
  }
}

// sum split-K partials (+bias) (+softshrink), write fp32 and/or fp16
__global__ void combine_k(const float* __restrict__ parts, int nparts, size_t pstride,
                          const float* __restrict__ bias, float* __restrict__ outf,
                          f16* __restrict__ outh, int total, int cols, int shrink) {
  int i = blockIdx.x * 256 + threadIdx.x;
  if (i >= total) return;
  float s = 0.f;
  for (int p = 0; p < nparts; ++p) s += parts[(size_t)p * pstride + i];
  if (bias) s += bias[i % cols];
  if (shrink) s = s > 0.5f ? s - 0.5f : (s < -0.5f ? s + 0.5f : 0.f);
  if (outf) outf[i] = s;
  if (outh) outh[i] = (f16)s;
}

extern "C" void kernel_launch(void* const* d_in, const int* in_sizes, int n_in,
                              void* d_out, int out_size, void* d_ws, size_t ws_size,
                              hipStream_t stream) {
  const float* x  = (const float*)d_in[0];
  const float* ow = (const float*)d_in[1];
  const float* dw = (const float*)d_in[2];
  const float* db = (const float*)d_in[3];
  const float* lw = (const float*)d_in[4];
  const float* lb = (const float*)d_in[5];
  float* out = (float*)d_out;

  const long KX = 50176;  // CIN*49
  char* ws = (char*)d_ws;
  size_t off = 0;
  auto alloc = [&](size_t bytes) {
    char* p = ws + off;
    off = (off + bytes + 255) & ~(size_t)255;
    return p;
  };
  f16*   ow_h = (f16*)  alloc((size_t)98 * KX * 2);         //   9.8 MB
  f16*   lw_h = (f16*)  alloc((size_t)2048 * 2048 * 2);     //   8.4 MB
  float* offp = (float*)alloc((size_t)49 * 1024 * 98 * 4);  //  19.7 MB
  float* offs = (float*)alloc((size_t)1024 * 98 * 4);       //   0.4 MB
  f16*   cols = (f16*)  alloc((size_t)1024 * KX * 2);       // 102.8 MB
  float* y1p  = (float*)alloc((size_t)8 * 1024 * 2048 * 4); //  67.1 MB
  f16*   y1h  = (f16*)  alloc((size_t)1024 * 2048 * 2);     //   4.2 MB
  float* y2p  = (float*)alloc((size_t)8 * 1024 * 2048 * 4); //  67.1 MB
  if (off > ws_size) return;  // workspace too small — fail visibly, don't fault

  // 1) fp32 -> fp16 conversions for the small weights (dw stays fp32; cvt'd in-GEMM)
  long n_ow = 98L * KX, n_lw = 2048L * 2048L;
  cvt_f32_to_f16<<<(unsigned)(n_ow / 8 / 256), 256, 0, stream>>>(ow, ow_h, n_ow);
  cvt_f32_to_f16<<<(unsigned)(n_lw / 8 / 256), 256, 0, stream>>>(lw, lw_h, n_lw);

  // 2) offset GEMM: [1024 x 98] = x(fp32) * ow^T, split-K 49 (grid 392, 32 iters)
  gemm_bt<true, false><<<8 * 1 * 49, 256, 0, stream>>>(
      x, ow_h, offp, 50176, 98, 8, 1, 1024, 1024);
  combine_k<<<(1024 * 98 + 255) / 256, 256, 0, stream>>>(
      offp, 49, (size_t)1024 * 98, nullptr, offs, nullptr, 1024 * 98, 98, 0);

  // 3) bilinear column build (fp16)
  build_cols<<<1024, 256, 0, stream>>>(x, offs, cols);

  // 4) deform GEMM: [1024 x 2048] = cols(fp16) * dw(fp32)^T, split-K 8 (grid 1024)
  gemm_bt<false, true><<<8 * 16 * 8, 256, 0, stream>>>(
      cols, dw, y1p, 50176, 2048, 8, 16, 6272, 1024);
  combine_k<<<(2097152 + 255) / 256, 256, 0, stream>>>(
      y1p, 8, (size_t)2097152, db, nullptr, y1h, 2097152, 2048, 0);

  // 5) linear GEMM: [1024 x 2048] = y1(fp16) * lw^T, split-K 8, then bias+softshrink
  gemm_bt<false, false><<<8 * 16 * 8, 256, 0, stream>>>(
      y1h, lw_h, y2p, 2048, 2048, 8, 16, 256, 1024);
  combine_k<<<(2097152 + 255) / 256, 256, 0, stream>>>(
      y2p, 8, (size_t)2097152, lb, out, nullptr, 2097152, 2048, 1);
}

// Round 3
// 1111.170 us; speedup vs baseline: 1.1410x; 1.1410x over previous
//
#include <hip/hip_runtime.h>

typedef _Float16 f16;
typedef _Float16 f16x8 __attribute__((ext_vector_type(8)));
typedef float f32x4 __attribute__((ext_vector_type(4)));

#define DEVI static __device__ __forceinline__

// async global->LDS 16B: lane i lands at (wave-uniform lds base) + i*16
DEVI void async_ld16(const void* g, void* l) {
  __builtin_amdgcn_global_load_lds(
      (const __attribute__((address_space(1))) unsigned int*)g,
      (__attribute__((address_space(3))) unsigned int*)l, 16, 0, 0);
}

// Byte offset of (row, logical k-quad) in a 128x32-f16 tile (64 B rows),
// XOR-swizzled so 16-lane frag reads are only 2-way bank aliased (free).
DEVI int sw_off(int row, int q) {
  return row * 64 + ((q ^ ((row >> 1) & 3)) << 4);
}

// C[M,N] (fp32 split-K partials) = A[M,K] * B[N,K]^T, B fp16 async-staged.
// A fp16 (async) or fp32 (in-kernel cvt — only for the small offset GEMM).
// 128x128 block tile, 4 waves of 64x64, 16x16x32 f16 MFMA, BK=32.
template<bool A_F32>
__global__ __launch_bounds__(256, 4)
void gemm_bt(const void* __restrict__ Aptr, const f16* __restrict__ Bt,
             float* __restrict__ Cpart, int ldK, int Nvalid,
             int mTiles, int nTiles, int kPerSplit, int Mtot) {
  __shared__ __align__(16) f16 As[128 * 32];
  __shared__ __align__(16) f16 Bs[128 * 32];

  // XCD swizzle: co-locate same-(ns,ks) M-tile groups on one XCD (grid % 8 == 0)
  int nb = gridDim.x;
  int bid = (blockIdx.x & 7) * (nb >> 3) + (blockIdx.x >> 3);
  int ms = bid % mTiles; bid /= mTiles;
  int ns = bid % nTiles; bid /= nTiles;
  int ks = bid;
  int m0 = ms * 128, n0 = ns * 128;
  int k0 = ks * kPerSplit;

  int tid = threadIdx.x;
  int w = tid >> 6, lane = tid & 63;
  int wrow = (w >> 1) * 64, wcol = (w & 1) * 64;
  int lrow = lane & 15, lquad = lane >> 4;

  f32x4 acc[4][4];
#pragma unroll
  for (int i = 0; i < 4; ++i)
#pragma unroll
    for (int j = 0; j < 4; ++j) acc[i][j] = (f32x4){0.f, 0.f, 0.f, 0.f};

  for (int kk = k0; kk < k0 + kPerSplit; kk += 32) {
    __syncthreads();  // previous iter's LDS reads done
    // ---- stage B tile (always async fp16) ----
#pragma unroll
    for (int s = 0; s < 2; ++s) {
      int rl = w * 32 + s * 16 + (lane >> 2);
      int qp = lane & 3;
      int q = qp ^ ((rl >> 1) & 3);
      int rb = n0 + rl; if (rb > Nvalid - 1) rb = Nvalid - 1;  // clamp (garbage cols unstored)
      async_ld16(Bt + (size_t)rb * ldK + kk + q * 8, &Bs[(w * 32 + s * 16) * 32]);
    }
    // ---- stage A tile ----
    if (!A_F32) {
      const f16* Ah = (const f16*)Aptr;
#pragma unroll
      for (int s = 0; s < 2; ++s) {
        int rl = w * 32 + s * 16 + (lane >> 2);
        int qp = lane & 3;
        int q = qp ^ ((rl >> 1) & 3);
        async_ld16(Ah + (size_t)(m0 + rl) * ldK + kk + q * 8, &As[(w * 32 + s * 16) * 32]);
      }
    } else {
      // fp32 A: load 16 floats/thread, cvt, swizzled ds_write (small GEMM only)
      const float* Af = (const float*)Aptr;
      int r = tid >> 1, half = tid & 1;
      const float* src = Af + (size_t)(m0 + r) * ldK + kk + half * 16;
#pragma unroll
      for (int u2 = 0; u2 < 2; ++u2) {
        f32x4 a = *(const f32x4*)(src + u2 * 8);
        f32x4 b = *(const f32x4*)(src + u2 * 8 + 4);
        f16x8 h;
        h[0] = (f16)a[0]; h[1] = (f16)a[1]; h[2] = (f16)a[2]; h[3] = (f16)a[3];
        h[4] = (f16)b[0]; h[5] = (f16)b[1]; h[6] = (f16)b[2]; h[7] = (f16)b[3];
        *(f16x8*)((char*)As + sw_off(r, half * 2 + u2)) = h;
      }
    }
    __syncthreads();  // drains vmcnt (async LDS) + lgkmcnt (ds_write)

    f16x8 af[4], bf[4];
#pragma unroll
    for (int i = 0; i < 4; ++i)
      af[i] = *(const f16x8*)((const char*)As + sw_off(wrow + i * 16 + lrow, lquad));
#pragma unroll
    for (int j = 0; j < 4; ++j)
      bf[j] = *(const f16x8*)((const char*)Bs + sw_off(wcol + j * 16 + lrow, lquad));
#pragma unroll
    for (int i = 0; i < 4; ++i)
#pragma unroll
      for (int j = 0; j < 4; ++j)
        acc[i][j] = __builtin_amdgcn_mfma_f32_16x16x32_f16(af[i], bf[j], acc[i][j], 0, 0, 0);
  }

  // C/D layout: col = lane&15, row = (lane>>4)*4 + reg  (m89/m91-verified)
  size_t base = (size_t)ks * Mtot * Nvalid;
#pragma unroll
  for (int i = 0; i < 4; ++i) {
    int row = m0 + wrow + i * 16 + lquad * 4;
#pragma unroll
    for (int j = 0; j < 4; ++j) {
      int col = n0 + wcol + j * 16 + lrow;
      if (col < Nvalid) {
#pragma unroll
        for (int r = 0; r < 4; ++r)
          Cpart[base + (size_t)(row + r) * Nvalid + col] = acc[i][j][r];
      }
    }
  }
}

__global__ void cvt_f32_to_f16(const float* __restrict__ in, f16* __restrict__ out, long n) {
  long idx = ((long)blockIdx.x * blockDim.x + threadIdx.x) * 8;
  if (idx + 8 <= n) {
    f32x4 a = *(const f32x4*)(in + idx);
    f32x4 b = *(const f32x4*)(in + idx + 4);
    f16x8 o;
    o[0] = (f16)a[0]; o[1] = (f16)a[1]; o[2] = (f16)a[2]; o[3] = (f16)a[3];
    o[4] = (f16)b[0]; o[5] = (f16)b[1]; o[6] = (f16)b[2]; o[7] = (f16)b[3];
    *(f16x8*)(out + idx) = o;
  }
}

// Build deform-conv columns, LDS-staged:
// block = (batch b, 128-channel chunk). Stage x[b][c0:c0+128][49] (25 KB) into
// LDS with coalesced f32x4; tap idx/weights (channel-uniform) in LDS tables;
// gather from LDS (broadcast-pattern, conflict-free); coalesced f16 stores.
__global__ __launch_bounds__(256, 4)
void build_cols(const float* __restrict__ x, const float* __restrict__ offs,
                f16* __restrict__ cols) {
  int b = blockIdx.x >> 3;
  int c0 = (blockIdx.x & 7) * 128;
  __shared__ __align__(16) float s_x[128 * 49];   // 25088 B, linear (no pad)
  __shared__ __align__(16) int   s_idx[49][4];
  __shared__ __align__(16) float s_w[49][4];
  int t = threadIdx.x;
  if (t < 49) {
    float dy = offs[b * 98 + 2 * t];
    float dx = offs[b * 98 + 2 * t + 1];
    float py = dy + (float)(t / 7);   // ky = p/7, base_y = 0
    float px = dx + (float)(t % 7);   // kx = p%7
    float fy0 = floorf(py), fx0 = floorf(px);
    int y0 = (int)fy0, x0 = (int)fx0;
    float fy = py - fy0, fx = px - fx0;
#pragma unroll
    for (int di = 0; di < 2; ++di)
#pragma unroll
      for (int dj = 0; dj < 2; ++dj) {
        int yi = y0 + di, xi = x0 + dj;
        bool valid = (yi >= 0) && (yi < 7) && (xi >= 0) && (xi < 7);
        int yc = yi < 0 ? 0 : (yi > 6 ? 6 : yi);
        int xc = xi < 0 ? 0 : (xi > 6 ? 6 : xi);
        float wy = di ? fy : 1.f - fy;
        float wx = dj ? fx : 1.f - fx;
        s_idx[t][di * 2 + dj] = yc * 7 + xc;
        s_w[t][di * 2 + dj] = valid ? wy * wx : 0.f;
      }
  }
  // stage x chunk: 6272 floats = 1568 f32x4, coalesced
  const f32x4* xs = (const f32x4*)(x + (size_t)b * 50176 + c0 * 49);
  f32x4* s4 = (f32x4*)s_x;
#pragma unroll
  for (int i = 0; i < 6; ++i) s4[t + i * 256] = xs[t + i * 256];
  if (t < 32) s4[1536 + t] = xs[1536 + t];
  __syncthreads();

  f16* cb = cols + (size_t)b * 50176 + c0 * 49;
#pragma unroll
  for (int i = 0; i < 25; ++i) {
    int o = t + i * 256;
    if (o < 6272) {
      unsigned c = (unsigned)o / 49u;
      unsigned p = (unsigned)o - c * 49u;
      int4  gi = *(const int4*)s_idx[p];
      float4 gw = *(const float4*)s_w[p];
      const float* row = s_x + c * 49;
      float v = gw.x * row[gi.x] + gw.y * row[gi.y]
              + gw.z * row[gi.z] + gw.w * row[gi.w];
      cb[o] = (f16)v;
    }
  }
}

// sum split-K partials (+bias) (+softshrink), write fp32 and/or fp16
__global__ void combine_k(const float* __restrict__ parts, int nparts, size_t pstride,
                          const float* __restrict__ bias, float* __restrict__ outf,
                          f16* __restrict__ outh, int total, int cols, int shrink) {
  int i = blockIdx.x * 256 + threadIdx.x;
  if (i >= total) return;
  float s = 0.f;
  for (int p = 0; p < nparts; ++p) s += parts[(size_t)p * pstride + i];
  if (bias) s += bias[i % cols];
  if (shrink) s = s > 0.5f ? s - 0.5f : (s < -0.5f ? s + 0.5f : 0.f);
  if (outf) outf[i] = s;
  if (outh) outh[i] = (f16)s;
}

extern "C" void kernel_launch(void* const* d_in, const int* in_sizes, int n_in,
                              void* d_out, int out_size, void* d_ws, size_t ws_size,
                              hipStream_t stream) {
  const float* x  = (const float*)d_in[0];
  const float* ow = (const float*)d_in[1];
  const float* dw = (const float*)d_in[2];
  const float* db = (const float*)d_in[3];
  const float* lw = (const float*)d_in[4];
  const float* lb = (const float*)d_in[5];
  float* out = (float*)d_out;

  const long KX = 50176;  // CIN*49
  char* ws = (char*)d_ws;
  size_t off = 0;
  auto alloc = [&](size_t bytes) {
    char* p = ws + off;
    off = (off + bytes + 255) & ~(size_t)255;
    return p;
  };
  f16*   dw_h = (f16*)  alloc((size_t)2048 * KX * 2);       // 205.5 MB
  f16*   ow_h = (f16*)  alloc((size_t)98 * KX * 2);         //   9.8 MB
  f16*   lw_h = (f16*)  alloc((size_t)2048 * 2048 * 2);     //   8.4 MB
  f16*   cols = (f16*)  alloc((size_t)1024 * KX * 2);       // 102.8 MB
  float* y1p  = (float*)alloc((size_t)8 * 1024 * 2048 * 4); //  67.1 MB
  f16*   y1h  = (f16*)  alloc((size_t)1024 * 2048 * 2);     //   4.2 MB
  // Aliases (time-disjoint): offsets live in y1p region (dead before deform
  // GEMM writes y1p); linear partials live in cols region (cols dead after
  // deform GEMM).
  float* offs = (float*)y1p;                                //   0.4 MB
  float* offp = (float*)((char*)y1p + (1u << 20));          //  39.4 MB
  float* y2p  = (float*)cols;                               //  67.1 MB
  if (off > ws_size) return;  // workspace too small — fail visibly, don't fault

  // 1) fp32 -> fp16 conversions (dw: 616 MB streamed, ~100 us)
  long n_dw = 2048L * KX, n_ow = 98L * KX, n_lw = 2048L * 2048L;
  cvt_f32_to_f16<<<(unsigned)(n_dw / 8 / 256), 256, 0, stream>>>(dw, dw_h, n_dw);
  cvt_f32_to_f16<<<(unsigned)(n_ow / 8 / 256), 256, 0, stream>>>(ow, ow_h, n_ow);
  cvt_f32_to_f16<<<(unsigned)(n_lw / 8 / 256), 256, 0, stream>>>(lw, lw_h, n_lw);

  // 2) offset GEMM: [1024 x 98] = x(fp32) * ow^T, split-K 98 (grid 784, 16 iters)
  gemm_bt<true><<<8 * 1 * 98, 256, 0, stream>>>(
      x, ow_h, offp, 50176, 98, 8, 1, 512, 1024);
  combine_k<<<(1024 * 98 + 255) / 256, 256, 0, stream>>>(
      offp, 98, (size_t)1024 * 98, nullptr, offs, nullptr, 1024 * 98, 98, 0);

  // 3) bilinear column build (LDS-staged, fp16 out)
  build_cols<<<1024 * 8, 256, 0, stream>>>(x, offs, cols);

  // 4) deform GEMM: [1024 x 2048] = cols(fp16) * dw_h^T, split-K 8 (grid 1024)
  gemm_bt<false><<<8 * 16 * 8, 256, 0, stream>>>(
      cols, dw_h, y1p, 50176, 2048, 8, 16, 6272, 1024);
  combine_k<<<(2097152 + 255) / 256, 256, 0, stream>>>(
      y1p, 8, (size_t)2097152, db, nullptr, y1h, 2097152, 2048, 0);

  // 5) linear GEMM: [1024 x 2048] = y1(fp16) * lw^T, split-K 8, then bias+softshrink
  gemm_bt<false><<<8 * 16 * 8, 256, 0, stream>>>(
      y1h, lw_h, y2p, 2048, 2048, 8, 16, 256, 1024);
  combine_k<<<(2097152 + 255) / 256, 256, 0, stream>>>(
      y2p, 8, (size_t)2097152, lb, out, nullptr, 2097152, 2048, 1);
}